// Round 1
// baseline (364.823 us; speedup 1.0000x reference)
//
#include <hip/hip_runtime.h>
#include <math.h>

#define NN 16        // nodes (4x4 grid)
#define HEADS 4
#define HID 64
#define CH 256       // HEADS*HID
#define TPB 256
#define XP_STRIDE 260
#define HT_STRIDE 20

// ---- per-dst source list (grid neighbors + self), branch-uniform ----
__device__ __forceinline__ int make_srcs(int d, int* srcs) {
    int i = d >> 2, j = d & 3, m = 0;
    srcs[m++] = d;                    // self loop
    if (j > 0) srcs[m++] = d - 1;
    if (j < 3) srcs[m++] = d + 1;
    if (i > 0) srcs[m++] = d - 4;
    if (i < 3) srcs[m++] = d + 4;
    return m;
}

// GEMM phase: xp[n][c] = sum_k ht[k][n] * W[k][c]   (c = threadIdx.x)
template<int K>
__device__ __forceinline__ void gemm_to_xp(const float* __restrict__ W,
                                           const float* s_ht, float* s_xp) {
    const int c = threadIdx.x;
    float acc[NN];
#pragma unroll
    for (int n = 0; n < NN; ++n) acc[n] = 0.f;
#pragma unroll 4
    for (int k = 0; k < K; ++k) {
        float w = W[k * CH + c];
        const float4* hp = reinterpret_cast<const float4*>(s_ht + k * HT_STRIDE);
        float4 h0 = hp[0], h1 = hp[1], h2 = hp[2], h3 = hp[3];
        acc[0]  += h0.x * w; acc[1]  += h0.y * w; acc[2]  += h0.z * w; acc[3]  += h0.w * w;
        acc[4]  += h1.x * w; acc[5]  += h1.y * w; acc[6]  += h1.z * w; acc[7]  += h1.w * w;
        acc[8]  += h2.x * w; acc[9]  += h2.y * w; acc[10] += h2.z * w; acc[11] += h2.w * w;
        acc[12] += h3.x * w; acc[13] += h3.y * w; acc[14] += h3.z * w; acc[15] += h3.w * w;
    }
#pragma unroll
    for (int n = 0; n < NN; ++n) s_xp[n * XP_STRIDE + c] = acc[n];
}

// attention coefficients: es/ed dots then per-(dst,head) softmax over in-edges
__device__ __forceinline__ void attention_coeffs(const float* __restrict__ a_src,
                                                 const float* __restrict__ a_dst,
                                                 const float* s_xp,
                                                 float* s_es, float* s_ed, float* s_alpha) {
    const int t = threadIdx.x;
    if (t < 128) {
        int n = t & 15, h = (t >> 4) & 3;
        const float* av  = (t < 64) ? a_src : a_dst;
        const float* row = s_xp + n * XP_STRIDE + h * HID;
        float acc = 0.f;
#pragma unroll 8
        for (int f = 0; f < HID; ++f) acc += row[f] * av[h * HID + f];
        ((t < 64) ? s_es : s_ed)[n * HEADS + h] = acc;
    }
    __syncthreads();
    if (t < 64) {
        int d = t & 15, h = t >> 4;
        int srcs[5];
        int m = make_srcs(d, srcs);
        float edv = s_ed[d * HEADS + h];
        float lg[5];
        float mx = -1e30f;
        for (int s = 0; s < m; ++s) {
            float l = s_es[srcs[s] * HEADS + h] + edv;
            l = (l > 0.f) ? l : 0.2f * l;          // leaky_relu 0.2
            lg[s] = l; mx = fmaxf(mx, l);
        }
        float sum = 0.f;
        for (int s = 0; s < m; ++s) { float w = expf(lg[s] - mx); lg[s] = w; sum += w; }
        float inv = 1.f / sum;
        for (int s = 0; s < m; ++s) s_alpha[(d * HEADS + h) * 5 + s] = lg[s] * inv;
    }
    __syncthreads();
}

// concat aggregation: ht[c][d] = relu(bias[c] + sum_s alpha[s,d,h]*xp[s][c])
__device__ __forceinline__ void aggregate_concat(const float* __restrict__ bias,
                                                 const float* s_xp, const float* s_alpha,
                                                 float* s_ht) {
    const int c = threadIdx.x;
    const int h = c >> 6;
    const float b = bias[c];
    for (int d = 0; d < NN; ++d) {
        int srcs[5];
        int m = make_srcs(d, srcs);
        float acc = b;
        for (int s = 0; s < m; ++s)
            acc += s_alpha[(d * HEADS + h) * 5 + s] * s_xp[srcs[s] * XP_STRIDE + c];
        s_ht[c * HT_STRIDE + d] = fmaxf(acc, 0.f);   // relu after gat0/gat1
    }
}

// final-layer aggregation: red[c] = sum_d sum_s alpha*xp  (no bias/relu here)
__device__ __forceinline__ void aggregate_mean(const float* s_xp, const float* s_alpha,
                                               float* s_red) {
    const int c = threadIdx.x;
    const int h = c >> 6;
    float acc = 0.f;
    for (int d = 0; d < NN; ++d) {
        int srcs[5];
        int m = make_srcs(d, srcs);
        for (int s = 0; s < m; ++s)
            acc += s_alpha[(d * HEADS + h) * 5 + s] * s_xp[srcs[s] * XP_STRIDE + c];
    }
    s_red[c] = acc;
}

__global__ __launch_bounds__(TPB) void gat_fused_kernel(
    const float* __restrict__ x,
    const float* __restrict__ in_w,  const float* __restrict__ in_b,
    const float* __restrict__ g0_w,  const float* __restrict__ g0_as,
    const float* __restrict__ g0_ad, const float* __restrict__ g0_b,
    const float* __restrict__ g1_w,  const float* __restrict__ g1_as,
    const float* __restrict__ g1_ad, const float* __restrict__ g1_b,
    const float* __restrict__ g2_w,  const float* __restrict__ g2_as,
    const float* __restrict__ g2_ad, const float* __restrict__ g2_b,
    const float* __restrict__ w1,    const float* __restrict__ b1,
    const float* __restrict__ ln1g,  const float* __restrict__ ln1b,
    const float* __restrict__ w2,    const float* __restrict__ b2,
    const float* __restrict__ ln2g,  const float* __restrict__ ln2b,
    float* __restrict__ out) {

    __shared__ __align__(16) float s_ht[256 * HT_STRIDE];   // [k][n] transposed feats
    __shared__ __align__(16) float s_xp[NN * XP_STRIDE];    // [n][c]
    __shared__ float s_red[256];
    __shared__ float s_es[NN * HEADS], s_ed[NN * HEADS];
    __shared__ float s_alpha[NN * HEADS * 5];

    const int b   = blockIdx.x;
    const int t   = threadIdx.x;

    // ---- load nodes: nodes[b][n][c] = x[b*256 + c*16 + n]; stash in xp area ----
    float* s_nodes = s_xp;              // 256 floats, dead before gat0 GEMM output
    s_nodes[t] = x[b * 256 + t];
    __syncthreads();

    // ---- h0 = relu(nodes @ in_w + in_b), stored transposed ht[f][n] ----
    {
        int f = t & 63, nb = t >> 6;
        for (int r = 0; r < 4; ++r) {
            int n = nb + 4 * r;
            float acc = in_b[f];
#pragma unroll
            for (int c = 0; c < 16; ++c) acc += s_nodes[c * 16 + n] * in_w[c * 64 + f];
            s_ht[f * HT_STRIDE + n] = fmaxf(acc, 0.f);
        }
    }
    __syncthreads();

    // ---- GAT layer 0 (K=64) ----
    gemm_to_xp<64>(g0_w, s_ht, s_xp);
    __syncthreads();
    attention_coeffs(g0_as, g0_ad, s_xp, s_es, s_ed, s_alpha);
    aggregate_concat(g0_b, s_xp, s_alpha, s_ht);
    __syncthreads();

    // ---- GAT layer 1 (K=256) ----
    gemm_to_xp<256>(g1_w, s_ht, s_xp);
    __syncthreads();
    attention_coeffs(g1_as, g1_ad, s_xp, s_es, s_ed, s_alpha);
    aggregate_concat(g1_b, s_xp, s_alpha, s_ht);
    __syncthreads();

    // ---- GAT layer 2 (K=256, mean over heads) ----
    gemm_to_xp<256>(g2_w, s_ht, s_xp);
    __syncthreads();
    attention_coeffs(g2_as, g2_ad, s_xp, s_es, s_ed, s_alpha);
    aggregate_mean(s_xp, s_alpha, s_red);
    __syncthreads();

    // ---- pool: g[f] = g2_b[f] + (sum over d and heads)/64 ; xp area now dead ----
    float* s_g  = s_xp;         // 64
    float* s_y  = s_xp + 64;    // 128 (pre-LN)
    float* s_y2 = s_xp + 192;   // 128 (post-LN relu)
    float* s_p2 = s_xp + 320;   // 256 (pre-LN)
    if (t < 64)
        s_g[t] = g2_b[t] + (s_red[t] + s_red[t + 64] + s_red[t + 128] + s_red[t + 192]) * (1.f / 64.f);
    __syncthreads();

    // ---- MLP layer 1: 64 -> 128, LN, relu ----
    if (t < 128) {
        float acc = b1[t];
#pragma unroll 8
        for (int k = 0; k < 64; ++k) acc += s_g[k] * w1[k * 128 + t];
        s_y[t] = acc;
    }
    __syncthreads();
    {
        float sum = 0.f, sq = 0.f;
        for (int k = 0; k < 128; ++k) { float v = s_y[k]; sum += v; sq += v * v; }
        float m = sum * (1.f / 128.f);
        float v = sq * (1.f / 128.f) - m * m;
        float r = rsqrtf(v + 1e-5f);
        if (t < 128) s_y2[t] = fmaxf((s_y[t] - m) * r * ln1g[t] + ln1b[t], 0.f);
    }
    __syncthreads();

    // ---- MLP layer 2: 128 -> 256, LN, relu ----
    float acc2 = b2[t];
#pragma unroll 8
    for (int k = 0; k < 128; ++k) acc2 += s_y2[k] * w2[k * 256 + t];
    s_p2[t] = acc2;
    __syncthreads();
    {
        float sum = 0.f, sq = 0.f;
        for (int k = 0; k < 256; ++k) { float v = s_p2[k]; sum += v; sq += v * v; }
        float m = sum * (1.f / 256.f);
        float v = sq * (1.f / 256.f) - m * m;
        float r = rsqrtf(v + 1e-5f);
        out[b * 256 + t] = fmaxf((acc2 - m) * r * ln2g[t] + ln2b[t], 0.f);
    }
}

extern "C" void kernel_launch(void* const* d_in, const int* in_sizes, int n_in,
                              void* d_out, int out_size, void* d_ws, size_t ws_size,
                              hipStream_t stream) {
    const float* x    = (const float*)d_in[0];
    const float* in_w = (const float*)d_in[1];
    const float* in_b = (const float*)d_in[2];
    const float* g0w  = (const float*)d_in[3];
    const float* g0as = (const float*)d_in[4];
    const float* g0ad = (const float*)d_in[5];
    const float* g0b  = (const float*)d_in[6];
    const float* g1w  = (const float*)d_in[7];
    const float* g1as = (const float*)d_in[8];
    const float* g1ad = (const float*)d_in[9];
    const float* g1b  = (const float*)d_in[10];
    const float* g2w  = (const float*)d_in[11];
    const float* g2as = (const float*)d_in[12];
    const float* g2ad = (const float*)d_in[13];
    const float* g2b  = (const float*)d_in[14];
    const float* w1   = (const float*)d_in[15];
    const float* b1   = (const float*)d_in[16];
    const float* ln1g = (const float*)d_in[17];
    const float* ln1b = (const float*)d_in[18];
    const float* w2   = (const float*)d_in[19];
    const float* b2   = (const float*)d_in[20];
    const float* ln2g = (const float*)d_in[21];
    const float* ln2b = (const float*)d_in[22];

    const int B = in_sizes[0] / 256;   // 4096: x is (B,16,4,4)

    gat_fused_kernel<<<B, TPB, 0, stream>>>(
        x, in_w, in_b,
        g0w, g0as, g0ad, g0b,
        g1w, g1as, g1ad, g1b,
        g2w, g2as, g2ad, g2b,
        w1, b1, ln1g, ln1b,
        w2, b2, ln2g, ln2b,
        (float*)d_out);
}

// Round 2
// 116.051 us; speedup vs baseline: 3.1437x; 3.1437x over previous
//
#include <hip/hip_runtime.h>
#include <math.h>

#define NN 16
#define TPB 256

typedef short bfrag __attribute__((ext_vector_type(8)));   // 8 x bf16 (4 VGPRs)
typedef float facc4 __attribute__((ext_vector_type(4)));   // 4 x f32 accum

__device__ __forceinline__ short f2bf(float x) {           // RNE f32 -> bf16
    unsigned u = __float_as_uint(x);
    unsigned r = (u + 0x7fffu + ((u >> 16) & 1u)) >> 16;
    return (short)r;
}

__device__ __forceinline__ int make_srcs(int d, int* srcs) {
    int i = d >> 2, j = d & 3, m = 0;
    srcs[m++] = d;
    if (j > 0) srcs[m++] = d - 1;
    if (j < 3) srcs[m++] = d + 1;
    if (i > 0) srcs[m++] = d - 4;
    if (i < 3) srcs[m++] = d + 4;
    return m;
}

__device__ __forceinline__ float wave_sum(float v) {
    v += __shfl_xor(v, 1);  v += __shfl_xor(v, 2);  v += __shfl_xor(v, 4);
    v += __shfl_xor(v, 8);  v += __shfl_xor(v, 16); v += __shfl_xor(v, 32);
    return v;
}

// ---- weight prep: fp32 (K x 256) -> bf16 fragments [s][nt][lane][j] ----
// element = W[(32s + 8*(l>>4) + j) * 256 + 16*nt + (l&15)]
__global__ void prep_w(const float* __restrict__ W, short* __restrict__ out, int total) {
    int u = blockIdx.x * 256 + threadIdx.x;
    if (u >= total) return;
    int j = u & 7, l = (u >> 3) & 63, nt = (u >> 9) & 15, s = u >> 13;
    int k = 32 * s + 8 * (l >> 4) + j;
    int c = 16 * nt + (l & 15);
    out[u] = f2bf(W[k * 256 + c]);
}

// ---- core of one GAT layer: GEMM (MFMA) + attn coeffs + softmax + MFMA aggregation ----
// s_ht: A operand, bf16 row-major [16][AST]; Wp: packed B fragments.
// Leaves aggregated (pre-bias) output in agg[4] (C/D layout: row=4g+r, col=64w+16t+ci).
template<int KSTEPS, int AST>
__device__ __forceinline__ void gat_core(
    const short* s_ht, const bfrag* __restrict__ Wp,
    const float* __restrict__ asrc, const float* __restrict__ adst,
    float* s_es, float* s_ed, short* s_alphaM, short* s_xpT,
    int t, facc4 agg[4]) {

    const int w = t >> 6, lane = t & 63, g = lane >> 4, ci = lane & 15;
    const facc4 fz = {0.f, 0.f, 0.f, 0.f};

    // ---- GEMM: xp[16][256] = ht @ W ----
    facc4 acc[4];
    acc[0] = fz; acc[1] = fz; acc[2] = fz; acc[3] = fz;
#pragma unroll 2
    for (int s = 0; s < KSTEPS; ++s) {
        bfrag a = *(const bfrag*)(s_ht + ci * AST + s * 32 + g * 8);
#pragma unroll
        for (int tt = 0; tt < 4; ++tt) {
            bfrag bf = Wp[(s * 16 + 4 * w + tt) * 64 + lane];
            acc[tt] = __builtin_amdgcn_mfma_f32_16x16x32_bf16(a, bf, acc[tt], 0, 0, 0);
        }
    }

    // ---- es/ed from accumulators (wave w == head w) ----
    float avs[4], avd[4];
#pragma unroll
    for (int tt = 0; tt < 4; ++tt) {
        avs[tt] = asrc[w * 64 + 16 * tt + ci];
        avd[tt] = adst[w * 64 + 16 * tt + ci];
    }
    float pe[4] = {0.f, 0.f, 0.f, 0.f}, pd[4] = {0.f, 0.f, 0.f, 0.f};
#pragma unroll
    for (int tt = 0; tt < 4; ++tt)
#pragma unroll
        for (int r = 0; r < 4; ++r) {
            pe[r] += acc[tt][r] * avs[tt];
            pd[r] += acc[tt][r] * avd[tt];
        }
#pragma unroll
    for (int r = 0; r < 4; ++r) {    // reduce across the 16-lane group
        pe[r] += __shfl_xor(pe[r], 1); pe[r] += __shfl_xor(pe[r], 2);
        pe[r] += __shfl_xor(pe[r], 4); pe[r] += __shfl_xor(pe[r], 8);
        pd[r] += __shfl_xor(pd[r], 1); pd[r] += __shfl_xor(pd[r], 2);
        pd[r] += __shfl_xor(pd[r], 4); pd[r] += __shfl_xor(pd[r], 8);
    }

    // ---- stash xp (bf16, transposed [col][node], stride 40, nodes 16..31 = zero pad) ----
#pragma unroll
    for (int tt = 0; tt < 4; ++tt)
#pragma unroll
        for (int r = 0; r < 4; ++r)
            s_xpT[(64 * w + 16 * tt + ci) * 40 + 4 * g + r] = f2bf(acc[tt][r]);

    if (ci == 0) {
#pragma unroll
        for (int r = 0; r < 4; ++r) {
            s_es[(4 * g + r) * 4 + w] = pe[r];
            s_ed[(4 * g + r) * 4 + w] = pd[r];
        }
    }
    __syncthreads();

    // ---- softmax over in-edges, write dense bf16 alpha matrix [h][d][src] ----
    if (t < 64) {
        int d = t & 15, h = t >> 4;
        int srcs[5];
        int m = make_srcs(d, srcs);
        float edv = s_ed[d * 4 + h];
        float lg[5];
        float mx = -1e30f;
        for (int i = 0; i < m; ++i) {
            float l = s_es[srcs[i] * 4 + h] + edv;
            l = (l > 0.f) ? l : 0.2f * l;
            lg[i] = l; mx = fmaxf(mx, l);
        }
        float sum = 0.f;
        for (int i = 0; i < m; ++i) { float e = __expf(lg[i] - mx); lg[i] = e; sum += e; }
        float inv = 1.f / sum;
        short* base = s_alphaM + (h * 16 + d) * 40;
        for (int i = 0; i < m; ++i) base[srcs[i]] = f2bf(lg[i] * inv);
        // non-neighbor + k>=16 slots stay zero (zeroed once at kernel start;
        // the neighbor support set is identical for all three layers)
    }
    __syncthreads();

    // ---- aggregation: out[d][col] = sum_s alpha[d][s] * xp[s][col]  (one MFMA per tile) ----
    bfrag af = *(const bfrag*)(s_alphaM + (w * 16 + ci) * 40 + g * 8);
#pragma unroll
    for (int tt = 0; tt < 4; ++tt) {
        bfrag xb = *(const bfrag*)(s_xpT + (64 * w + 16 * tt + ci) * 40 + g * 8);
        agg[tt] = __builtin_amdgcn_mfma_f32_16x16x32_bf16(af, xb, fz, 0, 0, 0);
    }
}

__global__ __launch_bounds__(TPB, 4) void gat_fused(
    const float* __restrict__ x,
    const float* __restrict__ in_w,  const float* __restrict__ in_b,
    const short* __restrict__ wsb,                       // packed bf16 weights
    const float* __restrict__ g0_as, const float* __restrict__ g0_ad, const float* __restrict__ g0_b,
    const float* __restrict__ g1_as, const float* __restrict__ g1_ad, const float* __restrict__ g1_b,
    const float* __restrict__ g2_as, const float* __restrict__ g2_ad, const float* __restrict__ g2_b,
    const float* __restrict__ w1,    const float* __restrict__ b1,
    const float* __restrict__ ln1g,  const float* __restrict__ ln1b,
    const float* __restrict__ w2,    const float* __restrict__ b2,
    const float* __restrict__ ln2g,  const float* __restrict__ ln2b,
    float* __restrict__ out) {

    __shared__ __align__(16) short s_ht[16 * 264];      // A operand (stride 72 for K=64, 264 for K=256)
    __shared__ __align__(16) short s_xpT[256 * 40];     // xp^T bf16, zero-padded K
    __shared__ __align__(16) short s_alphaM[64 * 40];   // dense alpha [h][d][k], zero-padded K
    __shared__ float s_es[64], s_ed[64];
    __shared__ float s_nodes[256];
    __shared__ float s_hsum[256];
    __shared__ __align__(16) float s_g[64];
    __shared__ __align__(16) float s_y2[128];
    __shared__ float s_part[8];

    const int b = blockIdx.x, t = threadIdx.x;
    const int w = t >> 6, lane = t & 63, g = lane >> 4, ci = lane & 15;

    // zero the padded LDS operand regions once; load node features
    {
        int* z1 = (int*)s_xpT;
        for (int i = t; i < 256 * 40 / 2; i += TPB) z1[i] = 0;
        int* z2 = (int*)s_alphaM;
        for (int i = t; i < 64 * 40 / 2; i += TPB) z2[i] = 0;
    }
    s_nodes[t] = x[b * 256 + t];
    __syncthreads();

    // ---- h0 = relu(nodes @ in_w + in_b) -> bf16 [16][72] ----
    {
        int f = t & 63, nb = t >> 6;
#pragma unroll
        for (int rr = 0; rr < 4; ++rr) {
            int n = nb + 4 * rr;
            float acc = in_b[f];
#pragma unroll
            for (int c = 0; c < 16; ++c) acc += s_nodes[c * 16 + n] * in_w[c * 64 + f];
            s_ht[n * 72 + f] = f2bf(fmaxf(acc, 0.f));
        }
    }
    __syncthreads();

    const bfrag* Wp0 = (const bfrag*)(wsb);
    const bfrag* Wp1 = (const bfrag*)(wsb + 16384);
    const bfrag* Wp2 = (const bfrag*)(wsb + 81920);

    facc4 agg[4];

    // ---- GAT 0 (K=64) ----
    gat_core<2, 72>(s_ht, Wp0, g0_as, g0_ad, s_es, s_ed, s_alphaM, s_xpT, t, agg);
#pragma unroll
    for (int tt = 0; tt < 4; ++tt)
#pragma unroll
        for (int r = 0; r < 4; ++r) {
            float v = agg[tt][r] + g0_b[64 * w + 16 * tt + ci];
            s_ht[(4 * g + r) * 264 + 64 * w + 16 * tt + ci] = f2bf(fmaxf(v, 0.f));
        }
    __syncthreads();

    // ---- GAT 1 (K=256) ----
    gat_core<8, 264>(s_ht, Wp1, g1_as, g1_ad, s_es, s_ed, s_alphaM, s_xpT, t, agg);
#pragma unroll
    for (int tt = 0; tt < 4; ++tt)
#pragma unroll
        for (int r = 0; r < 4; ++r) {
            float v = agg[tt][r] + g1_b[64 * w + 16 * tt + ci];
            s_ht[(4 * g + r) * 264 + 64 * w + 16 * tt + ci] = f2bf(fmaxf(v, 0.f));
        }
    __syncthreads();

    // ---- GAT 2 (K=256), mean over heads+nodes ----
    gat_core<8, 264>(s_ht, Wp2, g2_as, g2_ad, s_es, s_ed, s_alphaM, s_xpT, t, agg);
    {
        float cs[4];
#pragma unroll
        for (int tt = 0; tt < 4; ++tt) {
            cs[tt] = agg[tt][0] + agg[tt][1] + agg[tt][2] + agg[tt][3]; // sum rows in-lane
            cs[tt] += __shfl_xor(cs[tt], 16);                            // sum across groups
            cs[tt] += __shfl_xor(cs[tt], 32);
        }
        if (lane < 16) {
#pragma unroll
            for (int tt = 0; tt < 4; ++tt) s_hsum[w * 64 + 16 * tt + lane] = cs[tt];
        }
    }
    __syncthreads();
    if (t < 64)
        s_g[t] = g2_b[t] + (s_hsum[t] + s_hsum[64 + t] + s_hsum[128 + t] + s_hsum[192 + t]) * (1.f / 64.f);
    __syncthreads();

    // ---- MLP1: 64 -> 128, LN, relu ----
    float pre = 0.f;
    if (t < 128) {
        pre = b1[t];
        const float4* gv = (const float4*)s_g;
#pragma unroll
        for (int k4 = 0; k4 < 16; ++k4) {
            float4 gg = gv[k4];
            pre += gg.x * w1[(4 * k4 + 0) * 128 + t];
            pre += gg.y * w1[(4 * k4 + 1) * 128 + t];
            pre += gg.z * w1[(4 * k4 + 2) * 128 + t];
            pre += gg.w * w1[(4 * k4 + 3) * 128 + t];
        }
    }
    {
        float v = (t < 128) ? pre : 0.f;
        float v2 = v * v;
        v = wave_sum(v); v2 = wave_sum(v2);
        if (lane == 0) { s_part[w * 2] = v; s_part[w * 2 + 1] = v2; }
    }
    __syncthreads();
    {
        float sum = s_part[0] + s_part[2], sq = s_part[1] + s_part[3];
        float m = sum * (1.f / 128.f);
        float var = sq * (1.f / 128.f) - m * m;
        float rs = rsqrtf(var + 1e-5f);
        if (t < 128) s_y2[t] = fmaxf((pre - m) * rs * ln1g[t] + ln1b[t], 0.f);
    }
    __syncthreads();

    // ---- MLP2: 128 -> 256, LN, relu ----
    float pre2 = b2[t];
    {
        const float4* yv = (const float4*)s_y2;
#pragma unroll
        for (int k4 = 0; k4 < 32; ++k4) {
            float4 yy = yv[k4];
            pre2 += yy.x * w2[(4 * k4 + 0) * 256 + t];
            pre2 += yy.y * w2[(4 * k4 + 1) * 256 + t];
            pre2 += yy.z * w2[(4 * k4 + 2) * 256 + t];
            pre2 += yy.w * w2[(4 * k4 + 3) * 256 + t];
        }
    }
    {
        float v = wave_sum(pre2);
        float v2 = wave_sum(pre2 * pre2);
        if (lane == 0) { s_part[w * 2] = v; s_part[w * 2 + 1] = v2; }
    }
    __syncthreads();
    {
        float sum = s_part[0] + s_part[2] + s_part[4] + s_part[6];
        float sq  = s_part[1] + s_part[3] + s_part[5] + s_part[7];
        float m = sum * (1.f / 256.f);
        float var = sq * (1.f / 256.f) - m * m;
        float rs = rsqrtf(var + 1e-5f);
        out[b * 256 + t] = fmaxf((pre2 - m) * rs * ln2g[t] + ln2b[t], 0.f);
    }
}

extern "C" void kernel_launch(void* const* d_in, const int* in_sizes, int n_in,
                              void* d_out, int out_size, void* d_ws, size_t ws_size,
                              hipStream_t stream) {
    const float* x    = (const float*)d_in[0];
    const float* in_w = (const float*)d_in[1];
    const float* in_b = (const float*)d_in[2];
    const float* g0w  = (const float*)d_in[3];
    const float* g0as = (const float*)d_in[4];
    const float* g0ad = (const float*)d_in[5];
    const float* g0b  = (const float*)d_in[6];
    const float* g1w  = (const float*)d_in[7];
    const float* g1as = (const float*)d_in[8];
    const float* g1ad = (const float*)d_in[9];
    const float* g1b  = (const float*)d_in[10];
    const float* g2w  = (const float*)d_in[11];
    const float* g2as = (const float*)d_in[12];
    const float* g2ad = (const float*)d_in[13];
    const float* g2b  = (const float*)d_in[14];
    const float* w1   = (const float*)d_in[15];
    const float* b1   = (const float*)d_in[16];
    const float* ln1g = (const float*)d_in[17];
    const float* ln1b = (const float*)d_in[18];
    const float* w2   = (const float*)d_in[19];
    const float* b2   = (const float*)d_in[20];
    const float* ln2g = (const float*)d_in[21];
    const float* ln2b = (const float*)d_in[22];

    const int B = in_sizes[0] / 256;
    short* wsb = (short*)d_ws;

    // pack weights to bf16 fragment order (re-done every call: deterministic)
    prep_w<<<64,  256, 0, stream>>>(g0w, wsb,          16384);   // K=64 : 2 ksteps
    prep_w<<<256, 256, 0, stream>>>(g1w, wsb + 16384,  65536);   // K=256: 8 ksteps
    prep_w<<<256, 256, 0, stream>>>(g2w, wsb + 81920,  65536);

    gat_fused<<<B, TPB, 0, stream>>>(
        x, in_w, in_b, wsb,
        g0as, g0ad, g0b,
        g1as, g1ad, g1b,
        g2as, g2ad, g2b,
        w1, b1, ln1g, ln1b,
        w2, b2, ln2g, ln2b,
        (float*)d_out);
}

// Round 3
// 92.362 us; speedup vs baseline: 3.9499x; 1.2565x over previous
//
#include <hip/hip_runtime.h>
#include <math.h>

#define TPB 256
typedef short bfrag __attribute__((ext_vector_type(8)));   // 8 x bf16
typedef float facc4 __attribute__((ext_vector_type(4)));   // 4 x f32
typedef unsigned int u32;

// ws layout (in shorts)
#define O_INW 0        // 2048   : in_w packed (4 tiles, K=16 padded to 32)
#define O_G0  2048     // 17408  : gat0 W, 2 ksteps x 17 tiles (tile16 = fold)
#define O_G1  19456    // 69632  : gat1 W, 8 ksteps x 17 tiles
#define O_G2  89088    // 69632  : gat2 W
#define O_W1  158720   // 8192   : mlp w1, 2 ksteps x 8 tiles
#define O_W2  166912   // 32768  : mlp w2, 4 ksteps x 16 tiles

__device__ __forceinline__ short f2bf(float x) {           // RNE f32 -> bf16
    u32 u = __float_as_uint(x);
    u32 r = (u + 0x7fffu + ((u >> 16) & 1u)) >> 16;
    return (short)r;
}
__device__ __forceinline__ u32 pk2bf(float lo, float hi) {
    return ((u32)(unsigned short)f2bf(hi) << 16) | (u32)(unsigned short)f2bf(lo);
}

__device__ __forceinline__ int make_srcs(int d, int* srcs) {
    int i = d >> 2, j = d & 3, m = 0;
    srcs[m++] = d;
    if (j > 0) srcs[m++] = d - 1;
    if (j < 3) srcs[m++] = d + 1;
    if (i > 0) srcs[m++] = d - 4;
    if (i < 3) srcs[m++] = d + 4;
    return m;
}

// ============================ weight prep ============================
// B-fragment layout: out[((s*TSTR+nt)*64+l)*8+j] = bf(W[(32s+8*(l>>4)+j)*NCOL + 16nt + (l&15)])
__device__ __forceinline__ void pack_frag(const float* __restrict__ W, short* __restrict__ out,
                                          int blk, int NCOL, int TSTR) {
    int u = blk * 256 + threadIdx.x;
    int NT = NCOL >> 4;
    int j = u & 7, l = (u >> 3) & 63, q = u >> 9;
    int nt = q % NT, s = q / NT;
    int k = 32 * s + 8 * (l >> 4) + j;
    int c = 16 * nt + (l & 15);
    out[((s * TSTR + nt) * 64 + l) * 8 + j] = f2bf(W[k * NCOL + c]);
}

// fold tile (tile16): col 2h = W[:,h-block]@a_src[h], col 2h+1 = @a_dst[h], cols 8..15 = 0
__device__ __forceinline__ void pack_fold(const float* __restrict__ W,
                                          const float* __restrict__ as_, const float* __restrict__ ad_,
                                          short* __restrict__ out, int blk, int TSTR) {
    int u = blk * 256 + threadIdx.x;
    int j = u & 7, l = (u >> 3) & 63, s = u >> 9;
    int c = l & 15;
    int k = 32 * s + 8 * (l >> 4) + j;
    float v = 0.f;
    if (c < 8) {
        int h = c >> 1;
        const float* a = (c & 1) ? ad_ : as_;
        for (int f = 0; f < 64; ++f) v += W[k * 256 + h * 64 + f] * a[h * 64 + f];
    }
    out[((s * TSTR + 16) * 64 + l) * 8 + j] = f2bf(v);
}

__device__ __forceinline__ void pack_inw(const float* __restrict__ inw, short* __restrict__ out, int blk) {
    int u = blk * 256 + threadIdx.x;
    int j = u & 7, l = (u >> 3) & 63, nt = u >> 9;
    int k = 8 * (l >> 4) + j;
    out[u] = (k < 16) ? f2bf(inw[k * 64 + 16 * nt + (l & 15)]) : (short)0;
}

__global__ void prep_all(const float* __restrict__ g0w, const float* __restrict__ g1w,
                         const float* __restrict__ g2w, const float* __restrict__ mw1,
                         const float* __restrict__ mw2, const float* __restrict__ inw,
                         const float* __restrict__ g0as, const float* __restrict__ g0ad,
                         const float* __restrict__ g1as, const float* __restrict__ g1ad,
                         const float* __restrict__ g2as, const float* __restrict__ g2ad,
                         short* __restrict__ ws) {
    int blk = blockIdx.x;
    if      (blk < 64)  pack_frag(g0w, ws + O_G0, blk,        256, 17);
    else if (blk < 320) pack_frag(g1w, ws + O_G1, blk - 64,   256, 17);
    else if (blk < 576) pack_frag(g2w, ws + O_G2, blk - 320,  256, 17);
    else if (blk < 608) pack_frag(mw1, ws + O_W1, blk - 576,  128, 8);
    else if (blk < 736) pack_frag(mw2, ws + O_W2, blk - 608,  256, 16);
    else if (blk < 744) pack_inw(inw, ws + O_INW, blk - 736);
    else if (blk < 748) pack_fold(g0w, g0as, g0ad, ws + O_G0, blk - 744, 17);
    else if (blk < 764) pack_fold(g1w, g1as, g1ad, ws + O_G1, blk - 748, 17);
    else                pack_fold(g2w, g2as, g2ad, ws + O_G2, blk - 764, 17);
}

// ============================ GAT core ============================
template<int KSTEPS, int AST>
__device__ __forceinline__ void gat_core(
    const short* s_ht, const short* __restrict__ Wp,
    float* s_es, float* s_ed, short* s_alphaM, short* s_xpT,
    facc4 agg[4]) {

    const int t = threadIdx.x;
    const int w = t >> 6, lane = t & 63, g = lane >> 4, ci = lane & 15;
    const facc4 fz = {0.f, 0.f, 0.f, 0.f};
    const bfrag* Wf = (const bfrag*)Wp;

    facc4 acc[4] = {fz, fz, fz, fz};
    facc4 acce = fz;
#pragma unroll
    for (int s = 0; s < KSTEPS; ++s) {
        bfrag a = *(const bfrag*)(s_ht + ci * AST + s * 32 + g * 8);
#pragma unroll
        for (int tt = 0; tt < 4; ++tt)
            acc[tt] = __builtin_amdgcn_mfma_f32_16x16x32_bf16(a, Wf[(s * 17 + 4 * w + tt) * 64 + lane], acc[tt], 0, 0, 0);
        if (w == 0)   // es/ed fold tile
            acce = __builtin_amdgcn_mfma_f32_16x16x32_bf16(a, Wf[(s * 17 + 16) * 64 + lane], acce, 0, 0, 0);
    }

    // stash xp^T as bf16 (rows 4g+r contiguous -> one b64 write per tile)
#pragma unroll
    for (int tt = 0; tt < 4; ++tt) {
        u32 p0 = pk2bf(acc[tt][0], acc[tt][1]);
        u32 p1 = pk2bf(acc[tt][2], acc[tt][3]);
        *(uint2*)(s_xpT + (64 * w + 16 * tt + ci) * 40 + 4 * g) = make_uint2(p0, p1);
    }
    if (w == 0 && ci < 8) {     // es/ed from fold-tile accumulators
        float* dstp = (ci & 1) ? s_ed : s_es;
        int h = ci >> 1;
#pragma unroll
        for (int r = 0; r < 4; ++r) dstp[(4 * g + r) * 4 + h] = acce[r];
    }
    __syncthreads();

    if (t < 64) {               // softmax over in-edges -> dense bf16 alpha
        int d = t & 15, h = t >> 4;
        int srcs[5];
        int m = make_srcs(d, srcs);
        float edv = s_ed[d * 4 + h];
        float lg[5];
        float mx = -1e30f;
        for (int i = 0; i < m; ++i) {
            float l = s_es[srcs[i] * 4 + h] + edv;
            l = (l > 0.f) ? l : 0.2f * l;
            lg[i] = l; mx = fmaxf(mx, l);
        }
        float sum = 0.f;
        for (int i = 0; i < m; ++i) { float e = __expf(lg[i] - mx); lg[i] = e; sum += e; }
        float inv = 1.f / sum;
        short* base = s_alphaM + (h * 16 + d) * 40;
        for (int i = 0; i < m; ++i) base[srcs[i]] = f2bf(lg[i] * inv);
    }
    __syncthreads();

    // aggregation: one MFMA per output tile
    bfrag af = *(const bfrag*)(s_alphaM + (w * 16 + ci) * 40 + g * 8);
#pragma unroll
    for (int tt = 0; tt < 4; ++tt) {
        bfrag xb = *(const bfrag*)(s_xpT + (64 * w + 16 * tt + ci) * 40 + g * 8);
        agg[tt] = __builtin_amdgcn_mfma_f32_16x16x32_bf16(af, xb, fz, 0, 0, 0);
    }
}

// ============================ fused kernel ============================
__global__ __launch_bounds__(TPB, 4) void gat_fused(
    const float* __restrict__ x,  const float* __restrict__ in_b,
    const short* __restrict__ ws,
    const float* __restrict__ g0_b, const float* __restrict__ g1_b, const float* __restrict__ g2_b,
    const float* __restrict__ b1,   const float* __restrict__ ln1g, const float* __restrict__ ln1b,
    const float* __restrict__ b2,   const float* __restrict__ ln2g, const float* __restrict__ ln2b,
    float* __restrict__ out) {

    __shared__ __align__(16) short s_ht[16 * 264];
    __shared__ __align__(16) short s_xpT[256 * 40];
    __shared__ __align__(16) short s_alphaM[64 * 40];
    __shared__ float s_es[64], s_ed[64];
    __shared__ float s_hsum[256];
    __shared__ __align__(16) short s_gb[64];
    __shared__ __align__(16) short s_y2b[128];
    __shared__ float s_part[8];

    const int b = blockIdx.x, t = threadIdx.x;
    const int w = t >> 6, lane = t & 63, g = lane >> 4, ci = lane & 15;
    const facc4 fz = {0.f, 0.f, 0.f, 0.f};

    // zero K-pad regions once (shorts 16..31 of every xpT row; all of alphaM rows 0..31)
    *(uint4*)(s_xpT + t * 40 + 16) = make_uint4(0, 0, 0, 0);
    *(uint4*)(s_xpT + t * 40 + 24) = make_uint4(0, 0, 0, 0);
    *(uint4*)(s_alphaM + (t >> 2) * 40 + (t & 3) * 8) = make_uint4(0, 0, 0, 0);

    // ---- in-proj via MFMA: h0 = relu(nodes @ in_w + in_b) -> bf16 s_ht[n][f], stride 72 ----
    {
        bfrag a0 = {};
        if (g < 2) {
            float xv[8];
#pragma unroll
            for (int j = 0; j < 8; ++j) xv[j] = x[b * 256 + (8 * g + j) * 16 + ci];
            u32* ap = (u32*)&a0;
            ap[0] = pk2bf(xv[0], xv[1]); ap[1] = pk2bf(xv[2], xv[3]);
            ap[2] = pk2bf(xv[4], xv[5]); ap[3] = pk2bf(xv[6], xv[7]);
        }
        bfrag bw = ((const bfrag*)(ws + O_INW))[w * 64 + lane];
        facc4 h = __builtin_amdgcn_mfma_f32_16x16x32_bf16(a0, bw, fz, 0, 0, 0);
        float ib = in_b[16 * w + ci];
#pragma unroll
        for (int r = 0; r < 4; ++r)
            s_ht[(4 * g + r) * 72 + 16 * w + ci] = f2bf(fmaxf(h[r] + ib, 0.f));
    }
    __syncthreads();

    facc4 agg[4];

    // ---- GAT 0 (K=64) ----
    gat_core<2, 72>(s_ht, ws + O_G0, s_es, s_ed, s_alphaM, s_xpT, agg);
#pragma unroll
    for (int tt = 0; tt < 4; ++tt)
#pragma unroll
        for (int r = 0; r < 4; ++r) {
            float v = agg[tt][r] + g0_b[64 * w + 16 * tt + ci];
            s_ht[(4 * g + r) * 264 + 64 * w + 16 * tt + ci] = f2bf(fmaxf(v, 0.f));
        }
    __syncthreads();

    // ---- GAT 1 (K=256) ----
    gat_core<8, 264>(s_ht, ws + O_G1, s_es, s_ed, s_alphaM, s_xpT, agg);
#pragma unroll
    for (int tt = 0; tt < 4; ++tt)
#pragma unroll
        for (int r = 0; r < 4; ++r) {
            float v = agg[tt][r] + g1_b[64 * w + 16 * tt + ci];
            s_ht[(4 * g + r) * 264 + 64 * w + 16 * tt + ci] = f2bf(fmaxf(v, 0.f));
        }
    __syncthreads();

    // ---- GAT 2 (K=256) + mean pool over nodes & heads ----
    gat_core<8, 264>(s_ht, ws + O_G2, s_es, s_ed, s_alphaM, s_xpT, agg);
#pragma unroll
    for (int tt = 0; tt < 4; ++tt) {
        float c = agg[tt][0] + agg[tt][1] + agg[tt][2] + agg[tt][3];
        c += __shfl_xor(c, 16);
        c += __shfl_xor(c, 32);
        if (lane < 16) s_hsum[w * 64 + 16 * tt + lane] = c;
    }
    __syncthreads();
    if (t < 64)
        s_gb[t] = f2bf(g2_b[t] + (s_hsum[t] + s_hsum[64 + t] + s_hsum[128 + t] + s_hsum[192 + t]) * (1.f / 64.f));
    __syncthreads();

    // ---- MLP1: 64->128 via broadcast-A MFMA; LN; relu ----
    float v1[2];
    {
        const bfrag* W1f = (const bfrag*)(ws + O_W1);
        facc4 m0 = fz, m1 = fz;
#pragma unroll
        for (int s = 0; s < 2; ++s) {
            bfrag a = *(const bfrag*)(s_gb + 32 * s + 8 * g);
            m0 = __builtin_amdgcn_mfma_f32_16x16x32_bf16(a, W1f[(s * 8 + 2 * w + 0) * 64 + lane], m0, 0, 0, 0);
            m1 = __builtin_amdgcn_mfma_f32_16x16x32_bf16(a, W1f[(s * 8 + 2 * w + 1) * 64 + lane], m1, 0, 0, 0);
        }
        v1[0] = m0[0] + b1[32 * w + ci];
        v1[1] = m1[0] + b1[32 * w + 16 + ci];
    }
    {
        float u = v1[0] + v1[1];
        float u2 = v1[0] * v1[0] + v1[1] * v1[1];
        u += __shfl_xor(u, 1);  u += __shfl_xor(u, 2);  u += __shfl_xor(u, 4);  u += __shfl_xor(u, 8);
        u2 += __shfl_xor(u2, 1); u2 += __shfl_xor(u2, 2); u2 += __shfl_xor(u2, 4); u2 += __shfl_xor(u2, 8);
        if (lane == 0) { s_part[w] = u; s_part[4 + w] = u2; }
    }
    __syncthreads();
    {
        float sum = s_part[0] + s_part[1] + s_part[2] + s_part[3];
        float sq  = s_part[4] + s_part[5] + s_part[6] + s_part[7];
        float mn = sum * (1.f / 128.f);
        float var = sq * (1.f / 128.f) - mn * mn;
        float rs = rsqrtf(var + 1e-5f);
#pragma unroll
        for (int tt = 0; tt < 2; ++tt) {
            int col = 32 * w + 16 * tt + ci;
            float y = fmaxf((v1[tt] - mn) * rs * ln1g[col] + ln1b[col], 0.f);
            if (g == 0) s_y2b[col] = f2bf(y);
        }
    }
    __syncthreads();

    // ---- MLP2: 128->256 via broadcast-A MFMA; LN; relu; write out ----
    float v2[4];
    {
        const bfrag* W2f = (const bfrag*)(ws + O_W2);
        facc4 m[4] = {fz, fz, fz, fz};
#pragma unroll
        for (int s = 0; s < 4; ++s) {
            bfrag a = *(const bfrag*)(s_y2b + 32 * s + 8 * g);
#pragma unroll
            for (int tt = 0; tt < 4; ++tt)
                m[tt] = __builtin_amdgcn_mfma_f32_16x16x32_bf16(a, W2f[(s * 16 + 4 * w + tt) * 64 + lane], m[tt], 0, 0, 0);
        }
#pragma unroll
        for (int tt = 0; tt < 4; ++tt) v2[tt] = m[tt][0] + b2[64 * w + 16 * tt + ci];
    }
    {
        float u = v2[0] + v2[1] + v2[2] + v2[3];
        float u2 = v2[0] * v2[0] + v2[1] * v2[1] + v2[2] * v2[2] + v2[3] * v2[3];
        u += __shfl_xor(u, 1);  u += __shfl_xor(u, 2);  u += __shfl_xor(u, 4);  u += __shfl_xor(u, 8);
        u2 += __shfl_xor(u2, 1); u2 += __shfl_xor(u2, 2); u2 += __shfl_xor(u2, 4); u2 += __shfl_xor(u2, 8);
        if (lane == 0) { s_part[w] = u; s_part[4 + w] = u2; }
    }
    __syncthreads();
    {
        float sum = s_part[0] + s_part[1] + s_part[2] + s_part[3];
        float sq  = s_part[4] + s_part[5] + s_part[6] + s_part[7];
        float mn = sum * (1.f / 256.f);
        float var = sq * (1.f / 256.f) - mn * mn;
        float rs = rsqrtf(var + 1e-5f);
        if (g == 0) {
#pragma unroll
            for (int tt = 0; tt < 4; ++tt) {
                int col = 64 * w + 16 * tt + ci;
                out[b * 256 + col] = fmaxf((v2[tt] - mn) * rs * ln2g[col] + ln2b[col], 0.f);
            }
        }
    }
}

extern "C" void kernel_launch(void* const* d_in, const int* in_sizes, int n_in,
                              void* d_out, int out_size, void* d_ws, size_t ws_size,
                              hipStream_t stream) {
    const float* x    = (const float*)d_in[0];
    const float* in_w = (const float*)d_in[1];
    const float* in_b = (const float*)d_in[2];
    const float* g0w  = (const float*)d_in[3];
    const float* g0as = (const float*)d_in[4];
    const float* g0ad = (const float*)d_in[5];
    const float* g0b  = (const float*)d_in[6];
    const float* g1w  = (const float*)d_in[7];
    const float* g1as = (const float*)d_in[8];
    const float* g1ad = (const float*)d_in[9];
    const float* g1b  = (const float*)d_in[10];
    const float* g2w  = (const float*)d_in[11];
    const float* g2as = (const float*)d_in[12];
    const float* g2ad = (const float*)d_in[13];
    const float* g2b  = (const float*)d_in[14];
    const float* w1   = (const float*)d_in[15];
    const float* b1   = (const float*)d_in[16];
    const float* ln1g = (const float*)d_in[17];
    const float* ln1b = (const float*)d_in[18];
    const float* w2   = (const float*)d_in[19];
    const float* b2   = (const float*)d_in[20];
    const float* ln2g = (const float*)d_in[21];
    const float* ln2b = (const float*)d_in[22];

    const int B = in_sizes[0] / 256;
    short* wsb = (short*)d_ws;

    prep_all<<<780, 256, 0, stream>>>(g0w, g1w, g2w, w1, w2, in_w,
                                      g0as, g0ad, g1as, g1ad, g2as, g2ad, wsb);

    gat_fused<<<B, TPB, 0, stream>>>(
        x, in_b, wsb,
        g0b, g1b, g2b,
        b1, ln1g, ln1b,
        b2, ln2g, ln2b,
        (float*)d_out);
}

// Round 4
// 76.667 us; speedup vs baseline: 4.7585x; 1.2047x over previous
//
#include <hip/hip_runtime.h>
#include <math.h>

#define TPB 256
typedef short bfrag __attribute__((ext_vector_type(8)));   // 8 x bf16
typedef float facc4 __attribute__((ext_vector_type(4)));   // 4 x f32
typedef unsigned int u32;

// ws layout (in shorts)
#define O_INW 0        // 2048   : in_w packed (4 tiles, K=16 padded to 32)
#define O_G0  2048     // 17408  : gat0 W, 2 ksteps x 17 tiles (tile16 = fold)
#define O_G1  19456    // 69632  : gat1 W, 8 ksteps x 17 tiles
#define O_G2  89088    // 69632  : gat2 W
#define O_W1  158720   // 8192   : mlp w1, 2 ksteps x 8 tiles
#define O_W2  166912   // 32768  : mlp w2, 4 ksteps x 16 tiles

__device__ __forceinline__ short f2bf(float x) {           // RNE f32 -> bf16
    u32 u = __float_as_uint(x);
    u32 r = (u + 0x7fffu + ((u >> 16) & 1u)) >> 16;
    return (short)r;
}
__device__ __forceinline__ u32 pk2bf(float lo, float hi) {
    return ((u32)(unsigned short)f2bf(hi) << 16) | (u32)(unsigned short)f2bf(lo);
}

__device__ __forceinline__ int make_srcs(int d, int* srcs) {
    int i = d >> 2, j = d & 3, m = 0;
    srcs[m++] = d;
    if (j > 0) srcs[m++] = d - 1;
    if (j < 3) srcs[m++] = d + 1;
    if (i > 0) srcs[m++] = d - 4;
    if (i < 3) srcs[m++] = d + 4;
    return m;
}

// ============================ weight prep ============================
__device__ __forceinline__ void pack_frag(const float* __restrict__ W, short* __restrict__ out,
                                          int blk, int NCOL, int TSTR) {
    int u = blk * 256 + threadIdx.x;
    int NT = NCOL >> 4;
    int j = u & 7, l = (u >> 3) & 63, q = u >> 9;
    int nt = q % NT, s = q / NT;
    int k = 32 * s + 8 * (l >> 4) + j;
    int c = 16 * nt + (l & 15);
    out[((s * TSTR + nt) * 64 + l) * 8 + j] = f2bf(W[k * NCOL + c]);
}

// fold tile (tile16): col 2h = W[:,h-block]@a_src[h], col 2h+1 = @a_dst[h]
__device__ __forceinline__ void pack_fold(const float* __restrict__ W,
                                          const float* __restrict__ as_, const float* __restrict__ ad_,
                                          short* __restrict__ out, int blk, int TSTR) {
    int u = blk * 256 + threadIdx.x;
    int j = u & 7, l = (u >> 3) & 63, s = u >> 9;
    int c = l & 15;
    int k = 32 * s + 8 * (l >> 4) + j;
    float v = 0.f;
    if (c < 8) {
        int h = c >> 1;
        const float* a = (c & 1) ? ad_ : as_;
        for (int f = 0; f < 64; ++f) v += W[k * 256 + h * 64 + f] * a[h * 64 + f];
    }
    out[((s * TSTR + 16) * 64 + l) * 8 + j] = f2bf(v);
}

__device__ __forceinline__ void pack_inw(const float* __restrict__ inw, short* __restrict__ out, int blk) {
    int u = blk * 256 + threadIdx.x;
    int j = u & 7, l = (u >> 3) & 63, nt = u >> 9;
    int k = 8 * (l >> 4) + j;
    out[u] = (k < 16) ? f2bf(inw[k * 64 + 16 * nt + (l & 15)]) : (short)0;
}

__global__ void prep_all(const float* __restrict__ g0w, const float* __restrict__ g1w,
                         const float* __restrict__ g2w, const float* __restrict__ mw1,
                         const float* __restrict__ mw2, const float* __restrict__ inw,
                         const float* __restrict__ g0as, const float* __restrict__ g0ad,
                         const float* __restrict__ g1as, const float* __restrict__ g1ad,
                         const float* __restrict__ g2as, const float* __restrict__ g2ad,
                         short* __restrict__ ws) {
    int blk = blockIdx.x;
    if      (blk < 64)  pack_frag(g0w, ws + O_G0, blk,        256, 17);
    else if (blk < 320) pack_frag(g1w, ws + O_G1, blk - 64,   256, 17);
    else if (blk < 576) pack_frag(g2w, ws + O_G2, blk - 320,  256, 17);
    else if (blk < 608) pack_frag(mw1, ws + O_W1, blk - 576,  128, 8);
    else if (blk < 736) pack_frag(mw2, ws + O_W2, blk - 608,  256, 16);
    else if (blk < 744) pack_inw(inw, ws + O_INW, blk - 736);
    else if (blk < 748) pack_fold(g0w, g0as, g0ad, ws + O_G0, blk - 744, 17);
    else if (blk < 764) pack_fold(g1w, g1as, g1ad, ws + O_G1, blk - 748, 17);
    else                pack_fold(g2w, g2as, g2ad, ws + O_G2, blk - 764, 17);
}

// ============================ GAT core (2 graphs) ============================
// xpT rows: slots 0..15 = graph0 nodes, 16..31 = graph1 nodes.
// alphaM rows 0..63 = graph0 (alpha in slots 0..15), rows 64..127 = graph1 (slots 16..31).
template<int KSTEPS, int AST>
__device__ __forceinline__ void gat_core(
    const short* s_htA, const short* s_htB, const short* __restrict__ Wp,
    float (*s_es)[64], float (*s_ed)[64], short* s_alphaM, short* s_xpT,
    facc4 agg[2][4]) {

    const int t = threadIdx.x;
    const int w = t >> 6, lane = t & 63, g = lane >> 4, ci = lane & 15;
    const facc4 fz = {0.f, 0.f, 0.f, 0.f};
    const bfrag* Wf = (const bfrag*)Wp;

    facc4 acc[2][4] = {{fz, fz, fz, fz}, {fz, fz, fz, fz}};
    facc4 acce = fz;                       // fold: wave0 -> graph0, wave1 -> graph1
#pragma unroll
    for (int s = 0; s < KSTEPS; ++s) {
        bfrag a0 = *(const bfrag*)(s_htA + ci * AST + s * 32 + g * 8);
        bfrag a1 = *(const bfrag*)(s_htB + ci * AST + s * 32 + g * 8);
#pragma unroll
        for (int tt = 0; tt < 4; ++tt) {
            bfrag bf = Wf[(s * 17 + 4 * w + tt) * 64 + lane];
            acc[0][tt] = __builtin_amdgcn_mfma_f32_16x16x32_bf16(a0, bf, acc[0][tt], 0, 0, 0);
            acc[1][tt] = __builtin_amdgcn_mfma_f32_16x16x32_bf16(a1, bf, acc[1][tt], 0, 0, 0);
        }
        if (w < 2) {
            bfrag bfold = Wf[(s * 17 + 16) * 64 + lane];
            acce = __builtin_amdgcn_mfma_f32_16x16x32_bf16(w == 0 ? a0 : a1, bfold, acce, 0, 0, 0);
        }
    }

    // stash xp^T for both graphs (b64 packed writes)
#pragma unroll
    for (int gr = 0; gr < 2; ++gr)
#pragma unroll
        for (int tt = 0; tt < 4; ++tt) {
            u32 p0 = pk2bf(acc[gr][tt][0], acc[gr][tt][1]);
            u32 p1 = pk2bf(acc[gr][tt][2], acc[gr][tt][3]);
            *(uint2*)(s_xpT + (64 * w + 16 * tt + ci) * 40 + gr * 16 + 4 * g) = make_uint2(p0, p1);
        }
    if (w < 2 && ci < 8) {                 // es/ed from fold accumulators
        float* dstp = (ci & 1) ? s_ed[w] : s_es[w];
        int h = ci >> 1;
#pragma unroll
        for (int r = 0; r < 4; ++r) dstp[(4 * g + r) * 4 + h] = acce[r];
    }
    __syncthreads();

    if (t < 128) {                          // softmax, both graphs in parallel
        int gr = t >> 6, tl = t & 63, d = tl & 15, h = tl >> 4;
        int srcs[5];
        int m = make_srcs(d, srcs);
        float edv = s_ed[gr][d * 4 + h];
        float lg[5];
        float mx = -1e30f;
        for (int i = 0; i < m; ++i) {
            float l = s_es[gr][srcs[i] * 4 + h] + edv;
            l = (l > 0.f) ? l : 0.2f * l;
            lg[i] = l; mx = fmaxf(mx, l);
        }
        float sum = 0.f;
        for (int i = 0; i < m; ++i) { float e = __expf(lg[i] - mx); lg[i] = e; sum += e; }
        float inv = 1.f / sum;
        short* base = s_alphaM + (gr * 64 + h * 16 + d) * 40 + gr * 16;
        for (int i = 0; i < m; ++i) base[srcs[i]] = f2bf(lg[i] * inv);
    }
    __syncthreads();

    // aggregation: shared B-fragment (holds both graphs), 2 MFMA per tile
    bfrag af0 = *(const bfrag*)(s_alphaM + (w * 16 + ci) * 40 + g * 8);
    bfrag af1 = *(const bfrag*)(s_alphaM + (64 + w * 16 + ci) * 40 + g * 8);
#pragma unroll
    for (int tt = 0; tt < 4; ++tt) {
        bfrag xb = *(const bfrag*)(s_xpT + (64 * w + 16 * tt + ci) * 40 + g * 8);
        agg[0][tt] = __builtin_amdgcn_mfma_f32_16x16x32_bf16(af0, xb, fz, 0, 0, 0);
        agg[1][tt] = __builtin_amdgcn_mfma_f32_16x16x32_bf16(af1, xb, fz, 0, 0, 0);
    }
}

// ============================ fused kernel ============================
__global__ __launch_bounds__(TPB, 3) void gat_fused(
    const float* __restrict__ x,  const float* __restrict__ in_b,
    const short* __restrict__ ws,
    const float* __restrict__ g0_b, const float* __restrict__ g1_b, const float* __restrict__ g2_b,
    const float* __restrict__ b1,   const float* __restrict__ ln1g, const float* __restrict__ ln1b,
    const float* __restrict__ b2,   const float* __restrict__ ln2g, const float* __restrict__ ln2b,
    float* __restrict__ out) {

    __shared__ __align__(16) short s_ht[2][16 * 264];
    __shared__ __align__(16) short s_xpT[256 * 40];
    __shared__ __align__(16) short s_alphaM[128 * 40];
    __shared__ float s_es[2][64], s_ed[2][64];
    __shared__ float s_hsum[2][256];
    __shared__ __align__(16) short s_gb[2][64];
    __shared__ __align__(16) short s_y2b[2][128];
    __shared__ float s_part[2][8];

    const int b = blockIdx.x, t = threadIdx.x;
    const int w = t >> 6, lane = t & 63, g = lane >> 4, ci = lane & 15;
    const facc4 fz = {0.f, 0.f, 0.f, 0.f};

    // zero alphaM once (non-neighbor slots must stay 0 forever)
    for (int i = t; i < 640; i += TPB) ((uint4*)s_alphaM)[i] = make_uint4(0, 0, 0, 0);

    // ---- in-proj via MFMA for both graphs ----
    {
        bfrag a0 = {}, a1 = {};
        if (g < 2) {
            float xv0[8], xv1[8];
#pragma unroll
            for (int j = 0; j < 8; ++j) {
                xv0[j] = x[(2 * b)     * 256 + (8 * g + j) * 16 + ci];
                xv1[j] = x[(2 * b + 1) * 256 + (8 * g + j) * 16 + ci];
            }
            u32* ap0 = (u32*)&a0; u32* ap1 = (u32*)&a1;
#pragma unroll
            for (int j = 0; j < 4; ++j) {
                ap0[j] = pk2bf(xv0[2 * j], xv0[2 * j + 1]);
                ap1[j] = pk2bf(xv1[2 * j], xv1[2 * j + 1]);
            }
        }
        bfrag bw = ((const bfrag*)(ws + O_INW))[w * 64 + lane];
        facc4 h0 = __builtin_amdgcn_mfma_f32_16x16x32_bf16(a0, bw, fz, 0, 0, 0);
        facc4 h1 = __builtin_amdgcn_mfma_f32_16x16x32_bf16(a1, bw, fz, 0, 0, 0);
        float ib = in_b[16 * w + ci];
#pragma unroll
        for (int r = 0; r < 4; ++r) {
            s_ht[0][(4 * g + r) * 72 + 16 * w + ci] = f2bf(fmaxf(h0[r] + ib, 0.f));
            s_ht[1][(4 * g + r) * 72 + 16 * w + ci] = f2bf(fmaxf(h1[r] + ib, 0.f));
        }
    }
    __syncthreads();

    facc4 agg[2][4];

    // ---- GAT 0 (K=64) ----
    gat_core<2, 72>(s_ht[0], s_ht[1], ws + O_G0, s_es, s_ed, s_alphaM, s_xpT, agg);
#pragma unroll
    for (int tt = 0; tt < 4; ++tt) {
        float bb = g0_b[64 * w + 16 * tt + ci];
#pragma unroll
        for (int gr = 0; gr < 2; ++gr)
#pragma unroll
            for (int r = 0; r < 4; ++r)
                s_ht[gr][(4 * g + r) * 264 + 64 * w + 16 * tt + ci] = f2bf(fmaxf(agg[gr][tt][r] + bb, 0.f));
    }
    __syncthreads();

    // ---- GAT 1 (K=256) ----
    gat_core<8, 264>(s_ht[0], s_ht[1], ws + O_G1, s_es, s_ed, s_alphaM, s_xpT, agg);
#pragma unroll
    for (int tt = 0; tt < 4; ++tt) {
        float bb = g1_b[64 * w + 16 * tt + ci];
#pragma unroll
        for (int gr = 0; gr < 2; ++gr)
#pragma unroll
            for (int r = 0; r < 4; ++r)
                s_ht[gr][(4 * g + r) * 264 + 64 * w + 16 * tt + ci] = f2bf(fmaxf(agg[gr][tt][r] + bb, 0.f));
    }
    __syncthreads();

    // ---- GAT 2 (K=256) + mean pool ----
    gat_core<8, 264>(s_ht[0], s_ht[1], ws + O_G2, s_es, s_ed, s_alphaM, s_xpT, agg);
#pragma unroll
    for (int gr = 0; gr < 2; ++gr)
#pragma unroll
        for (int tt = 0; tt < 4; ++tt) {
            float c = agg[gr][tt][0] + agg[gr][tt][1] + agg[gr][tt][2] + agg[gr][tt][3];
            c += __shfl_xor(c, 16);
            c += __shfl_xor(c, 32);
            if (lane < 16) s_hsum[gr][w * 64 + 16 * tt + lane] = c;
        }
    __syncthreads();
    if (t < 128) {
        int gr = t >> 6, f = t & 63;
        s_gb[gr][f] = f2bf(g2_b[f] +
            (s_hsum[gr][f] + s_hsum[gr][64 + f] + s_hsum[gr][128 + f] + s_hsum[gr][192 + f]) * (1.f / 64.f));
    }
    __syncthreads();

    // ---- MLP1: 64->128, 2-row broadcast A (row gr = graph gr); LN; relu ----
    float v1[2][2];
    {
        const bfrag* W1f = (const bfrag*)(ws + O_W1);
        facc4 m0 = fz, m1 = fz;
#pragma unroll
        for (int s = 0; s < 2; ++s) {
            bfrag a = {};
            if (ci < 2) a = *(const bfrag*)(&s_gb[ci][0] + 32 * s + 8 * g);
            m0 = __builtin_amdgcn_mfma_f32_16x16x32_bf16(a, W1f[(s * 8 + 2 * w + 0) * 64 + lane], m0, 0, 0, 0);
            m1 = __builtin_amdgcn_mfma_f32_16x16x32_bf16(a, W1f[(s * 8 + 2 * w + 1) * 64 + lane], m1, 0, 0, 0);
        }
        float bb0 = b1[32 * w + ci], bb1 = b1[32 * w + 16 + ci];
        v1[0][0] = m0[0] + bb0; v1[1][0] = m0[1] + bb0;   // valid on g==0 lanes
        v1[0][1] = m1[0] + bb1; v1[1][1] = m1[1] + bb1;
    }
    {
#pragma unroll
        for (int gr = 0; gr < 2; ++gr) {
            float u = v1[gr][0] + v1[gr][1];
            float q = v1[gr][0] * v1[gr][0] + v1[gr][1] * v1[gr][1];
            u += __shfl_xor(u, 1); u += __shfl_xor(u, 2); u += __shfl_xor(u, 4); u += __shfl_xor(u, 8);
            q += __shfl_xor(q, 1); q += __shfl_xor(q, 2); q += __shfl_xor(q, 4); q += __shfl_xor(q, 8);
            if (lane == 0) { s_part[gr][w] = u; s_part[gr][4 + w] = q; }
        }
    }
    __syncthreads();
#pragma unroll
    for (int gr = 0; gr < 2; ++gr) {
        float sum = s_part[gr][0] + s_part[gr][1] + s_part[gr][2] + s_part[gr][3];
        float sq  = s_part[gr][4] + s_part[gr][5] + s_part[gr][6] + s_part[gr][7];
        float mn = sum * (1.f / 128.f);
        float var = sq * (1.f / 128.f) - mn * mn;
        float rs = rsqrtf(var + 1e-5f);
        if (g == 0) {
#pragma unroll
            for (int tt = 0; tt < 2; ++tt) {
                int col = 32 * w + 16 * tt + ci;
                s_y2b[gr][col] = f2bf(fmaxf((v1[gr][tt] - mn) * rs * ln1g[col] + ln1b[col], 0.f));
            }
        }
    }
    __syncthreads();

    // ---- MLP2: 128->256, 2-row broadcast A; LN; relu; out ----
    float v2[2][4];
    {
        const bfrag* W2f = (const bfrag*)(ws + O_W2);
        facc4 m[4] = {fz, fz, fz, fz};
#pragma unroll
        for (int s = 0; s < 4; ++s) {
            bfrag a = {};
            if (ci < 2) a = *(const bfrag*)(&s_y2b[ci][0] + 32 * s + 8 * g);
#pragma unroll
            for (int tt = 0; tt < 4; ++tt)
                m[tt] = __builtin_amdgcn_mfma_f32_16x16x32_bf16(a, W2f[(s * 16 + 4 * w + tt) * 64 + lane], m[tt], 0, 0, 0);
        }
#pragma unroll
        for (int tt = 0; tt < 4; ++tt) {
            float bb = b2[64 * w + 16 * tt + ci];
            v2[0][tt] = m[tt][0] + bb;
            v2[1][tt] = m[tt][1] + bb;
        }
    }
    {
#pragma unroll
        for (int gr = 0; gr < 2; ++gr) {
            float u = v2[gr][0] + v2[gr][1] + v2[gr][2] + v2[gr][3];
            float q = v2[gr][0] * v2[gr][0] + v2[gr][1] * v2[gr][1] + v2[gr][2] * v2[gr][2] + v2[gr][3] * v2[gr][3];
            u += __shfl_xor(u, 1); u += __shfl_xor(u, 2); u += __shfl_xor(u, 4); u += __shfl_xor(u, 8);
            q += __shfl_xor(q, 1); q += __shfl_xor(q, 2); q += __shfl_xor(q, 4); q += __shfl_xor(q, 8);
            if (lane == 0) { s_part[gr][w] = u; s_part[gr][4 + w] = q; }
        }
    }
    __syncthreads();
#pragma unroll
    for (int gr = 0; gr < 2; ++gr) {
        float sum = s_part[gr][0] + s_part[gr][1] + s_part[gr][2] + s_part[gr][3];
        float sq  = s_part[gr][4] + s_part[gr][5] + s_part[gr][6] + s_part[gr][7];
        float mn = sum * (1.f / 256.f);
        float var = sq * (1.f / 256.f) - mn * mn;
        float rs = rsqrtf(var + 1e-5f);
        if (g == 0) {
#pragma unroll
            for (int tt = 0; tt < 4; ++tt) {
                int col = 64 * w + 16 * tt + ci;
                out[(2 * b + gr) * 256 + col] = fmaxf((v2[gr][tt] - mn) * rs * ln2g[col] + ln2b[col], 0.f);
            }
        }
    }
}

extern "C" void kernel_launch(void* const* d_in, const int* in_sizes, int n_in,
                              void* d_out, int out_size, void* d_ws, size_t ws_size,
                              hipStream_t stream) {
    const float* x    = (const float*)d_in[0];
    const float* in_w = (const float*)d_in[1];
    const float* in_b = (const float*)d_in[2];
    const float* g0w  = (const float*)d_in[3];
    const float* g0as = (const float*)d_in[4];
    const float* g0ad = (const float*)d_in[5];
    const float* g0b  = (const float*)d_in[6];
    const float* g1w  = (const float*)d_in[7];
    const float* g1as = (const float*)d_in[8];
    const float* g1ad = (const float*)d_in[9];
    const float* g1b  = (const float*)d_in[10];
    const float* g2w  = (const float*)d_in[11];
    const float* g2as = (const float*)d_in[12];
    const float* g2ad = (const float*)d_in[13];
    const float* g2b  = (const float*)d_in[14];
    const float* w1   = (const float*)d_in[15];
    const float* b1   = (const float*)d_in[16];
    const float* ln1g = (const float*)d_in[17];
    const float* ln1b = (const float*)d_in[18];
    const float* w2   = (const float*)d_in[19];
    const float* b2   = (const float*)d_in[20];
    const float* ln2g = (const float*)d_in[21];
    const float* ln2b = (const float*)d_in[22];

    const int B = in_sizes[0] / 256;
    short* wsb = (short*)d_ws;

    prep_all<<<780, 256, 0, stream>>>(g0w, g1w, g2w, w1, w2, in_w,
                                      g0as, g0ad, g1as, g1ad, g2as, g2ad, wsb);

    gat_fused<<<B / 2, TPB, 0, stream>>>(
        x, in_b, wsb,
        g0b, g1b, g2b,
        b1, ln1g, ln1b,
        b2, ln2g, ln2b,
        (float*)d_out);
}